// Round 9
// baseline (1238.508 us; speedup 1.0000x reference)
//
#include <hip/hip_runtime.h>
#include <hip/hip_bf16.h>
#include <stdint.h>

// LSTM-CRF forward loss. B=128 L=256 V=6000 E=128 RV=300 RD=100 H=256 C=33
// DIN=428 (pad to 448). Pipeline:
//   pack_weights -> pack_A -> gemm_xg (gate-major X2 u16 layout)
//   -> lstm_recur (16 wg; 2 phase-offset 8-row chunks/block; Whh pinned;
//      lane-redistributed activations) -> emis_k -> golden_k -> crf_k -> fin_k

typedef unsigned short u16;
typedef __attribute__((ext_vector_type(8))) __bf16 bf16x8;
typedef __attribute__((ext_vector_type(4))) float f32x4;

struct __align__(8) u16x4 { u16 x, y, z, w; };

typedef const void __attribute__((address_space(1))) gas_t;
typedef void __attribute__((address_space(3))) las_t;

static __device__ __forceinline__ void gload16(const void* g, void* l) {
  __builtin_amdgcn_global_load_lds((gas_t*)g, (las_t*)l, 16, 0, 0);
}

static __device__ __forceinline__ u16 f2b(float x) {
  uint32_t u = __builtin_bit_cast(uint32_t, x);
  uint32_t r = u + 0x7fffu + ((u >> 16) & 1u);
  return (u16)(r >> 16);
}
static __device__ __forceinline__ float b2lo(uint32_t u) {
  return __builtin_bit_cast(float, u << 16);
}
static __device__ __forceinline__ float b2hi(uint32_t u) {
  return __builtin_bit_cast(float, u & 0xffff0000u);
}
static __device__ __forceinline__ float sigf(float x) {
  return __builtin_amdgcn_rcpf(1.f + __expf(-x));
}
static __device__ __forceinline__ float tanh_(float x) {
  return 1.f - 2.f * __builtin_amdgcn_rcpf(1.f + __expf(2.f * x));
}
static __device__ __forceinline__ f32x4 MFMA(bf16x8 a, bf16x8 b, f32x4 c) {
  return __builtin_amdgcn_mfma_f32_16x16x32_bf16(a, b, c, 0, 0, 0);
}

// ---------------- pack weights ----------------
// WihP[2048][448] bf16; bias[2048] f32 = bih+bhh; WclsP[48][512] bf16;
// WhhF8: fp8 e4m3 B-fragments, long-index ((d*8+v)*64 + gj*8+kf)*64 + lane,
//   gj = gate*2+jf; byte e: Whh_d[gate*256+v*32+jf*16+(lane&15)][kf*32+(lane>>4)*8+e]
__global__ __launch_bounds__(256) void pack_weights(
    const float* __restrict__ Wih_f, const float* __restrict__ Wih_b,
    const float* __restrict__ Whh_f, const float* __restrict__ Whh_b,
    const float* __restrict__ bih_f, const float* __restrict__ bhh_f,
    const float* __restrict__ bih_b, const float* __restrict__ bhh_b,
    const float* __restrict__ Wcls,
    u16* __restrict__ WihP, unsigned int* __restrict__ WhhF8,
    float* __restrict__ biasP, u16* __restrict__ WclsP) {
  int idx = blockIdx.x * 256 + threadIdx.x;
  if (idx < 917504) {                       // 2*1024*448
    int d = idx / 458752;
    int rem = idx - d * 458752;
    int r = rem / 448, k = rem - r * 448;
    const float* W = d ? Wih_b : Wih_f;
    WihP[idx] = (k < 428) ? f2b(W[r * 428 + k]) : (u16)0;
  } else if (idx < 919552) {                // bias 2048
    int j = idx - 917504;
    int r = j & 1023;
    biasP[j] = (j >> 10) ? (bih_b[r] + bhh_b[r]) : (bih_f[r] + bhh_f[r]);
  } else if (idx < 944128) {                // Wcls 48*512
    int j = idx - 919552;
    int r = j >> 9, k = j & 511;
    WclsP[j] = (r < 33) ? f2b(Wcls[r * 512 + k]) : (u16)0;
  } else if (idx < 1075200) {               // WhhF8: 131072 dwords
    int q = idx - 944128;
    int eh = q & 1, li = (q >> 1) & 63, fi = (q >> 7) & 63;
    int v = (q >> 13) & 7, dd = q >> 16;
    int l16 = li & 15, g = li >> 4;
    int kf = fi & 7, gj = fi >> 3;
    int gate = gj >> 1, jf = gj & 1;
    int row = gate * 256 + v * 32 + jf * 16 + l16;
    int col = kf * 32 + g * 8 + eh * 4;
    const float* W = dd ? Whh_b : Whh_f;
    float4 f = *(const float4*)(W + (size_t)row * 256 + col);
    unsigned int r01 = __builtin_amdgcn_cvt_pk_fp8_f32(f.x, f.y, 0u, false) & 0xffffu;
    unsigned int r23 = __builtin_amdgcn_cvt_pk_fp8_f32(f.z, f.w, 0u, false) & 0xffffu;
    WhhF8[q] = r01 | (r23 << 16);
  }
}

// ---------------- gather + pack A: [32768][448] bf16 ----------------
__global__ __launch_bounds__(256) void pack_A(const int* __restrict__ data,
    const int* __restrict__ onerad, const float* __restrict__ embed,
    const float* __restrict__ rad, u16* __restrict__ A) {
  int idx = blockIdx.x * 256 + threadIdx.x;
  int m = idx / 112;
  int c = idx - m * 112;
  int k0 = c * 4;
  float4 vv;
  if (k0 < 128)      vv = *(const float4*)(embed + (size_t)data[m] * 128 + k0);
  else if (k0 < 228) vv = *(const float4*)(rad + (size_t)onerad[m] * 100 + (k0 - 128));
  else if (k0 < 328) vv = *(const float4*)(rad + (size_t)onerad[32768 + m] * 100 + (k0 - 228));
  else if (k0 < 428) vv = *(const float4*)(rad + (size_t)onerad[65536 + m] * 100 + (k0 - 328));
  else               vv = make_float4(0.f, 0.f, 0.f, 0.f);
  u16x4 o4 = { f2b(vv.x), f2b(vv.y), f2b(vv.z), f2b(vv.w) };
  *(u16x4*)(A + (size_t)m * 448 + k0) = o4;
}

// ---------------- xg GEMM: X2 = gate-major(A @ Wih^T + bias) ----------------
// X2 u16 layout per d (33554432 u16): idx = R*1024 + v*128 + jf*64 + l16*4 + gate,
// R = m*256+t; col = d*1024 + gate*256 + v*32 + jf*16 + l16.
__global__ __launch_bounds__(256) void gemm_xg(const u16* __restrict__ A,
    const u16* __restrict__ Bw, const float* __restrict__ bias,
    u16* __restrict__ X2) {
  __shared__ u16 As[4096];
  __shared__ u16 Bs[4096];
  int bid = blockIdx.x;
  int mt = bid >> 4, nt = bid & 15;
  int m0 = mt * 128, n0 = nt * 128;
  int tid = threadIdx.x;
  int w = tid >> 6, lane = tid & 63, l16 = lane & 15, g = lane >> 4;
  int wr = w >> 1, wc = w & 1;
  int srow = tid >> 2, sch = tid & 3;
  f32x4 zero4 = {0.f, 0.f, 0.f, 0.f};
  f32x4 acc[4][4];
#pragma unroll
  for (int i = 0; i < 4; ++i)
#pragma unroll
    for (int j = 0; j < 4; ++j) acc[i][j] = zero4;
  for (int kk = 0; kk < 14; ++kk) {
    int kb = kk * 32;
    gload16(A + (size_t)(m0 + srow) * 448 + kb + sch * 8, (char*)As + tid * 16);
    gload16(A + (size_t)(m0 + srow + 64) * 448 + kb + sch * 8, (char*)As + 4096 + tid * 16);
    gload16(Bw + (size_t)(n0 + srow) * 448 + kb + sch * 8, (char*)Bs + tid * 16);
    gload16(Bw + (size_t)(n0 + srow + 64) * 448 + kb + sch * 8, (char*)Bs + 4096 + tid * 16);
    __syncthreads();
    bf16x8 af[4], bfr[4];
#pragma unroll
    for (int i = 0; i < 4; ++i) {
      af[i]  = *(const bf16x8*)((const char*)As + (wr * 64 + i * 16 + l16) * 64 + g * 16);
      bfr[i] = *(const bf16x8*)((const char*)Bs + (wc * 64 + i * 16 + l16) * 64 + g * 16);
    }
#pragma unroll
    for (int i = 0; i < 4; ++i)
#pragma unroll
      for (int j = 0; j < 4; ++j)
        acc[i][j] = MFMA(af[i], bfr[j], acc[i][j]);
    __syncthreads();
  }
  float bv[4];
#pragma unroll
  for (int j = 0; j < 4; ++j) bv[j] = bias[n0 + wc * 64 + j * 16 + l16];
#pragma unroll
  for (int i = 0; i < 4; ++i)
#pragma unroll
    for (int j = 0; j < 4; ++j) {
      int col = n0 + wc * 64 + j * 16 + l16;
      int dd = col >> 10, c = col & 1023;
      int gate = c >> 8, hid = c & 255;
      int vv = hid >> 5, jf2 = (hid >> 4) & 1, lc = hid & 15;
      size_t base = (size_t)dd * 33554432 + (size_t)vv * 128 + jf2 * 64 + lc * 4 + gate;
#pragma unroll
      for (int r = 0; r < 4; ++r) {
        int row = m0 + wr * 64 + i * 16 + g * 4 + r;
        X2[base + (size_t)row * 1024] = f2b(acc[i][j][r] + bv[j]);
      }
    }
}

// ---------------- LSTM recurrence: phase-offset 2x8-row chunks ----------------
// 16 blocks x 512 thr (2dir x 8 groups x 16 rows = chunks A,B of 8 rows).
// Whh pinned (64 longs/lane). MFMA M=16 tile, rows 8-15 zero. Activations
// lane-redistributed: lower 32 lanes = jf0 cols, upper = jf1 via shfl_xor(32).
// Segments: S1 = MFMA_A || trans_B(t-1); S2 = MFMA_B || trans_A(t). hfA/hfB
// single-buffered (read/write in opposite segments). Raw barrier fences.
#define PIN(n) long q##n; \
  asm volatile("global_load_dwordx2 %0, %1, off" : "=v"(q##n) : "v"(wbase + (n) * 512));
#define MMG(acc, gj, bn) \
  acc[gj] = __builtin_amdgcn_mfma_f32_16x16x32_fp8_fp8(a, bn, acc[gj], 0, 0, 0);
#define KSTEP(acc, fr, kf, B0, B1, B2, B3, B4, B5, B6, B7) { \
  long a = fr[(kf) * 64 + lane]; \
  MMG(acc, 0, B0) MMG(acc, 1, B1) MMG(acc, 2, B2) MMG(acc, 3, B3) \
  MMG(acc, 4, B4) MMG(acc, 5, B5) MMG(acc, 6, B6) MMG(acc, 7, B7) }
#define MFMA_PHASE(acc, hf) { \
  const long* fr = (const long*)(hf); \
  acc[0] = zero4; acc[1] = zero4; acc[2] = zero4; acc[3] = zero4; \
  acc[4] = zero4; acc[5] = zero4; acc[6] = zero4; acc[7] = zero4; \
  KSTEP(acc, fr, 0, q0, q8,  q16, q24, q32, q40, q48, q56) \
  KSTEP(acc, fr, 1, q1, q9,  q17, q25, q33, q41, q49, q57) \
  KSTEP(acc, fr, 2, q2, q10, q18, q26, q34, q42, q50, q58) \
  KSTEP(acc, fr, 3, q3, q11, q19, q27, q35, q43, q51, q59) \
  KSTEP(acc, fr, 4, q4, q12, q20, q28, q36, q44, q52, q60) \
  KSTEP(acc, fr, 5, q5, q13, q21, q29, q37, q45, q53, q61) \
  KSTEP(acc, fr, 6, q6, q14, q22, q30, q38, q46, q54, q62) \
  KSTEP(acc, fr, 7, q7, q15, q23, q31, q39, q47, q55, q63) }
#define TRANS(acc, cst, hf, sb, px) { \
  _Pragma("unroll") \
  for (int r = 0; r < 4; ++r) { \
    float o0 = __shfl_xor(acc[1][r], 32); \
    float o1 = __shfl_xor(acc[3][r], 32); \
    float o2 = __shfl_xor(acc[5][r], 32); \
    float o3 = __shfl_xor(acc[7][r], 32); \
    float iv = (lo32 ? acc[0][r] : o0) + b2lo(px[r].x); \
    float fv = (lo32 ? acc[2][r] : o1) + b2hi(px[r].x); \
    float gv = (lo32 ? acc[4][r] : o2) + b2lo(px[r].y); \
    float ov = (lo32 ? acc[6][r] : o3) + b2hi(px[r].y); \
    float cn = sigf(fv) * cst[r] + sigf(iv) * tanh_(gv); \
    cst[r] = cn; \
    float hv = sigf(ov) * tanh_(cn); \
    hf[fwoff + r * 8] = \
        (unsigned char)__builtin_amdgcn_cvt_pk_fp8_f32(hv, hv, 0u, false); \
    *(u16*)(sb[r] + voff_st) = f2b(hv); \
  } }
#define BUMP4(p, s) { p[0] += s; p[1] += s; p[2] += s; p[3] += s; }
#define LOADPX(px, pb) { \
  px[0] = *(const uint2*)(pb[0] + voff_px); \
  px[1] = *(const uint2*)(pb[1] + voff_px); \
  px[2] = *(const uint2*)(pb[2] + voff_px); \
  px[3] = *(const uint2*)(pb[3] + voff_px); }
#define FENCE { __builtin_amdgcn_sched_barrier(0); \
  asm volatile("s_waitcnt lgkmcnt(0)"); \
  __builtin_amdgcn_s_barrier(); \
  __builtin_amdgcn_sched_barrier(0); }

__global__ __launch_bounds__(512, 1) void lstm_recur(const u16* __restrict__ xg,
    const unsigned char* __restrict__ WhhF8, u16* __restrict__ outh) {
  __shared__ unsigned char hfA[4096];
  __shared__ unsigned char hfB[4096];
  int blk = blockIdx.x;
  int d = blk >> 3, c16 = blk & 7;
  int rowA0 = c16 * 16, rowB0 = c16 * 16 + 8;
  int tid = threadIdx.x;
  int v = tid >> 6, lane = tid & 63, l16 = lane & 15, g = lane >> 4;
  int jfL = g >> 1, gl = g & 1;
  bool lo32 = (lane < 32);

  const char* wbase = (const char*)WhhF8 + ((size_t)(d * 8 + v) * 4096 + lane) * 8;
  PIN(0)  PIN(1)  PIN(2)  PIN(3)  PIN(4)  PIN(5)  PIN(6)  PIN(7)
  PIN(8)  PIN(9)  PIN(10) PIN(11) PIN(12) PIN(13) PIN(14) PIN(15)
  PIN(16) PIN(17) PIN(18) PIN(19) PIN(20) PIN(21) PIN(22) PIN(23)
  PIN(24) PIN(25) PIN(26) PIN(27) PIN(28) PIN(29) PIN(30) PIN(31)
  PIN(32) PIN(33) PIN(34) PIN(35) PIN(36) PIN(37) PIN(38) PIN(39)
  PIN(40) PIN(41) PIN(42) PIN(43) PIN(44) PIN(45) PIN(46) PIN(47)
  PIN(48) PIN(49) PIN(50) PIN(51) PIN(52) PIN(53) PIN(54) PIN(55)
  PIN(56) PIN(57) PIN(58) PIN(59) PIN(60) PIN(61) PIN(62) PIN(63)

  for (int i = tid; i < 1024; i += 512) { ((int*)hfA)[i] = 0; ((int*)hfB)[i] = 0; }

  int t0 = d ? 255 : 0;
  int tpx = d ? -2048 : 2048;    // bytes per t-step in X2 (1024 u16/row-step)
  int tob = d ? -1024 : 1024;    // bytes per t-step in outh (512 u16)

  const char* X2b = (const char*)xg + (size_t)d * 67108864;
  char* outhb = (char*)outh;
  const char* pbA[4]; const char* pbB[4];
  char* sbA[4]; char* sbB[4];
#pragma unroll
  for (int r = 0; r < 4; ++r) {
    pbA[r] = X2b + ((size_t)(rowA0 + r) * 256 + t0) * 2048;
    pbB[r] = X2b + ((size_t)(rowB0 + r) * 256 + t0) * 2048;
    sbA[r] = outhb + (((size_t)(rowA0 + r) * 256 + t0) * 512 + d * 256) * 2;
    sbB[r] = outhb + (((size_t)(rowB0 + r) * 256 + t0) * 512 + d * 256) * 2;
  }
  int voff_px = gl * 2097152 + (v * 128 + jfL * 64 + l16 * 4) * 2;
  int voff_st = gl * 1048576 + (v * 32 + jfL * 16 + l16) * 2;
  int fwoff = (v * 64 + jfL * 32 + (l16 >> 3) * 16 + gl * 4) * 8 + (l16 & 7);

  uint2 pxA[4], pxB[4];
  LOADPX(pxA, pbA);
  LOADPX(pxB, pbB);

  asm volatile("s_waitcnt vmcnt(0)" ::: "memory");
  __builtin_amdgcn_sched_barrier(0);

  f32x4 zero4 = {0.f, 0.f, 0.f, 0.f};
  f32x4 cstA = zero4, cstB = zero4;
  f32x4 accA[8], accB[8];
  __syncthreads();

#pragma unroll 1
  for (int tt = 0; tt < 256; ++tt) {
    // ---- S1: MFMA_A(t) || trans_B(t-1) ----
    MFMA_PHASE(accA, hfA);
    if (tt > 0) {
      TRANS(accB, cstB, hfB, sbB, pxB);
      BUMP4(sbB, tob); BUMP4(pbB, tpx);
      LOADPX(pxB, pbB);
    }
    FENCE;
    // ---- S2: MFMA_B(t) || trans_A(t) ----
    MFMA_PHASE(accB, hfB);
    TRANS(accA, cstA, hfA, sbA, pxA);
    BUMP4(sbA, tob); BUMP4(pbA, tpx);
    LOADPX(pxA, pbA);
    FENCE;
  }
  // epilogue: trans_B for the final timestep
  TRANS(accB, cstB, hfB, sbB, pxB);
}

// ---------------- emission: [32768][33] f32 = outh @ Wcls^T + bcls ----------------
__global__ __launch_bounds__(256) void emis_k(const u16* __restrict__ outh,
    const u16* __restrict__ WclsP, const float* __restrict__ bcls,
    float* __restrict__ emiB) {
  int tid = threadIdx.x;
  int w = tid >> 6, lane = tid & 63, l16 = lane & 15, g = lane >> 4;
  int mrow = blockIdx.x * 64 + w * 16;
  f32x4 zero4 = {0.f, 0.f, 0.f, 0.f};
  f32x4 acc[3] = {zero4, zero4, zero4};
#pragma unroll
  for (int kf = 0; kf < 16; ++kf) {
    bf16x8 a = *(const bf16x8*)(outh + (size_t)(mrow + l16) * 512 + kf * 32 + g * 8);
#pragma unroll
    for (int nf = 0; nf < 3; ++nf) {
      bf16x8 bb = *(const bf16x8*)(WclsP + (size_t)(nf * 16 + l16) * 512 + kf * 32 + g * 8);
      acc[nf] = MFMA(a, bb, acc[nf]);
    }
  }
#pragma unroll
  for (int nf = 0; nf < 3; ++nf) {
    int c = nf * 16 + l16;
    if (c < 33) {
      float bc = bcls[c];
#pragma unroll
      for (int r = 0; r < 4; ++r)
        emiB[(size_t)(mrow + g * 4 + r) * 33 + c] = acc[nf][r] + bc;
    }
  }
}

// ---------------- golden path score per batch row ----------------
__global__ __launch_bounds__(256) void golden_k(const int* __restrict__ tag,
    const float* __restrict__ emiB, const float* __restrict__ T,
    float* __restrict__ gpart) {
  int b = blockIdx.x, l = threadIdx.x;
  int tg = tag[b * 256 + l];
  float val = 0.f;
  if (tg != 0) {
    int prev = (l == 0) ? 31 : tag[b * 256 + l - 1];
    val = emiB[(size_t)(b * 256 + l) * 33 + tg] + T[prev * 33 + tg];
  }
#pragma unroll
  for (int o = 32; o > 0; o >>= 1) val += __shfl_down(val, o);
  __shared__ float red[4];
  if ((threadIdx.x & 63) == 0) red[threadIdx.x >> 6] = val;
  __syncthreads();
  if (threadIdx.x == 0) gpart[b] = red[0] + red[1] + red[2] + red[3];
}

// ---------------- CRF forward (logsumexp scan), 1 wave per batch row ----------------
__global__ __launch_bounds__(64) void crf_k(const int* __restrict__ tag,
    const float* __restrict__ emiB, const float* __restrict__ T,
    float* __restrict__ endsc) {
  int b = blockIdx.x;
  int lane = threadIdx.x;
  __shared__ float Ts[1089];
  __shared__ float sc[33];
  for (int i = lane; i < 1089; i += 64) Ts[i] = T[i];
  int cnt = 0;
  for (int i = lane; i < 256; i += 64) cnt += (tag[b * 256 + i] != 0) ? 1 : 0;
#pragma unroll
  for (int o = 1; o < 64; o <<= 1) cnt += __shfl_xor(cnt, o);
  int len = cnt;
  __syncthreads();
  int c = lane;
  float tcol[33];
  if (c < 33) {
#pragma unroll
    for (int p = 0; p < 33; ++p) tcol[p] = Ts[p * 33 + c];
    sc[c] = emiB[(size_t)(b * 256) * 33 + c] + tcol[31];   // START=31
  }
  __syncthreads();
#pragma unroll 1
  for (int t = 1; t < 256; ++t) {
    if (t >= len) break;
    float nv = 0.f;
    if (c < 33) {
      float ec = emiB[(size_t)(b * 256 + t) * 33 + c];
      float vb[33];
      float mx = -3.0e38f;
#pragma unroll
      for (int p = 0; p < 33; ++p) { vb[p] = sc[p] + tcol[p]; mx = fmaxf(mx, vb[p]); }
      float s = 0.f;
#pragma unroll
      for (int p = 0; p < 33; ++p) s += __expf(vb[p] - mx);
      nv = ec + mx + __logf(s);
    }
    __syncthreads();
    if (c < 33) sc[c] = nv;
    __syncthreads();
  }
  if (lane == 0) endsc[b] = sc[32];   // END=32
}

// ---------------- finalize ----------------
__global__ __launch_bounds__(64) void fin_k(const float* __restrict__ gpart,
    const float* __restrict__ endsc, float* __restrict__ out) {
  int l = threadIdx.x;
  float v = (endsc[l] - gpart[l]) + (endsc[l + 64] - gpart[l + 64]);
#pragma unroll
  for (int o = 32; o > 0; o >>= 1) v += __shfl_down(v, o);
  if (l == 0) out[0] = v / 128.f;
}

extern "C" void kernel_launch(void* const* d_in, const int* in_sizes, int n_in,
                              void* d_out, int out_size, void* d_ws, size_t ws_size,
                              hipStream_t stream) {
  const int*   batch_data   = (const int*)d_in[0];
  const int*   batch_onerad = (const int*)d_in[1];
  const int*   batch_tag    = (const int*)d_in[2];
  const float* embed        = (const float*)d_in[3];
  const float* rad_embed    = (const float*)d_in[4];
  const float* Wih_f = (const float*)d_in[5];
  const float* Whh_f = (const float*)d_in[6];
  const float* bih_f = (const float*)d_in[7];
  const float* bhh_f = (const float*)d_in[8];
  const float* Wih_b = (const float*)d_in[9];
  const float* Whh_b = (const float*)d_in[10];
  const float* bih_b = (const float*)d_in[11];
  const float* bhh_b = (const float*)d_in[12];
  const float* Wcls  = (const float*)d_in[13];
  const float* bcls  = (const float*)d_in[14];
  const float* trans = (const float*)d_in[15];

  // workspace layout (~203.9 MB)
  char* ws = (char*)d_ws;
  u16*   Apack = (u16*)  (ws + 0);            // 29360128
  u16*   X2    = (u16*)  (ws + 29360128);     // 134217728 (gate-major xg)
  u16*   WihP  = (u16*)  (ws + 163577856);    // 1835008
  unsigned int* WhhF8 = (unsigned int*)(ws + 165412864); // 524288
  float* biasP = (float*)(ws + 165937152);    // 8192
  u16*   WclsP = (u16*)  (ws + 165945344);    // 49152
  u16*   outh  = (u16*)  (ws + 165994496);    // 33554432
  float* emiB  = (float*)(ws + 199548928);    // 4325376
  float* gpart = (float*)(ws + 203874304);    // 512
  float* endsc = (float*)(ws + 203874816);    // 512

  pack_weights<<<4200, 256, 0, stream>>>(Wih_f, Wih_b, Whh_f, Whh_b, bih_f, bhh_f,
                                         bih_b, bhh_b, Wcls, WihP, WhhF8, biasP, WclsP);
  pack_A<<<14336, 256, 0, stream>>>(batch_data, batch_onerad, embed, rad_embed, Apack);
  gemm_xg<<<4096, 256, 0, stream>>>(Apack, WihP, biasP, X2);
  lstm_recur<<<16, 512, 0, stream>>>(X2, (const unsigned char*)WhhF8, outh);
  emis_k<<<512, 256, 0, stream>>>(outh, WclsP, bcls, emiB);
  golden_k<<<128, 256, 0, stream>>>(batch_tag, emiB, trans, gpart);
  crf_k<<<128, 64, 0, stream>>>(batch_tag, emiB, trans, endsc);
  fin_k<<<1, 64, 0, stream>>>(gpart, endsc, (float*)d_out);
}

// Round 10
// 820.314 us; speedup vs baseline: 1.5098x; 1.5098x over previous
//
#include <hip/hip_runtime.h>
#include <hip/hip_bf16.h>
#include <stdint.h>

// LSTM-CRF forward loss. B=128 L=256 V=6000 E=128 RV=300 RD=100 H=256 C=33
// DIN=428 (pad to 448). Pipeline:
//   pack_weights -> pack_A -> gemm_xg (gate-major X2 u16 layout)
//   -> lstm_recur (32 wg; ONE 8-row chunk/block; Whh pinned; jf-redistributed
//      activations; 1 fence/step) -> emis_k -> golden_k -> crf_k -> fin_k

typedef unsigned short u16;
typedef __attribute__((ext_vector_type(8))) __bf16 bf16x8;
typedef __attribute__((ext_vector_type(4))) float f32x4;

struct __align__(8) u16x4 { u16 x, y, z, w; };

typedef const void __attribute__((address_space(1))) gas_t;
typedef void __attribute__((address_space(3))) las_t;

static __device__ __forceinline__ void gload16(const void* g, void* l) {
  __builtin_amdgcn_global_load_lds((gas_t*)g, (las_t*)l, 16, 0, 0);
}

static __device__ __forceinline__ u16 f2b(float x) {
  uint32_t u = __builtin_bit_cast(uint32_t, x);
  uint32_t r = u + 0x7fffu + ((u >> 16) & 1u);
  return (u16)(r >> 16);
}
static __device__ __forceinline__ float b2lo(uint32_t u) {
  return __builtin_bit_cast(float, u << 16);
}
static __device__ __forceinline__ float b2hi(uint32_t u) {
  return __builtin_bit_cast(float, u & 0xffff0000u);
}
static __device__ __forceinline__ float sigf(float x) {
  return __builtin_amdgcn_rcpf(1.f + __expf(-x));
}
static __device__ __forceinline__ float tanh_(float x) {
  return 1.f - 2.f * __builtin_amdgcn_rcpf(1.f + __expf(2.f * x));
}
static __device__ __forceinline__ f32x4 MFMA(bf16x8 a, bf16x8 b, f32x4 c) {
  return __builtin_amdgcn_mfma_f32_16x16x32_bf16(a, b, c, 0, 0, 0);
}

// ---------------- pack weights ----------------
// WihP[2048][448] bf16; bias[2048] f32 = bih+bhh; WclsP[48][512] bf16;
// WhhF8: fp8 e4m3 B-fragments, long-index ((d*8+v)*64 + gj*8+kf)*64 + lane,
//   gj = gate*2+jf; byte e: Whh_d[gate*256+v*32+jf*16+(lane&15)][kf*32+(lane>>4)*8+e]
__global__ __launch_bounds__(256) void pack_weights(
    const float* __restrict__ Wih_f, const float* __restrict__ Wih_b,
    const float* __restrict__ Whh_f, const float* __restrict__ Whh_b,
    const float* __restrict__ bih_f, const float* __restrict__ bhh_f,
    const float* __restrict__ bih_b, const float* __restrict__ bhh_b,
    const float* __restrict__ Wcls,
    u16* __restrict__ WihP, unsigned int* __restrict__ WhhF8,
    float* __restrict__ biasP, u16* __restrict__ WclsP) {
  int idx = blockIdx.x * 256 + threadIdx.x;
  if (idx < 917504) {                       // 2*1024*448
    int d = idx / 458752;
    int rem = idx - d * 458752;
    int r = rem / 448, k = rem - r * 448;
    const float* W = d ? Wih_b : Wih_f;
    WihP[idx] = (k < 428) ? f2b(W[r * 428 + k]) : (u16)0;
  } else if (idx < 919552) {                // bias 2048
    int j = idx - 917504;
    int r = j & 1023;
    biasP[j] = (j >> 10) ? (bih_b[r] + bhh_b[r]) : (bih_f[r] + bhh_f[r]);
  } else if (idx < 944128) {                // Wcls 48*512
    int j = idx - 919552;
    int r = j >> 9, k = j & 511;
    WclsP[j] = (r < 33) ? f2b(Wcls[r * 512 + k]) : (u16)0;
  } else if (idx < 1075200) {               // WhhF8: 131072 dwords
    int q = idx - 944128;
    int eh = q & 1, li = (q >> 1) & 63, fi = (q >> 7) & 63;
    int v = (q >> 13) & 7, dd = q >> 16;
    int l16 = li & 15, g = li >> 4;
    int kf = fi & 7, gj = fi >> 3;
    int gate = gj >> 1, jf = gj & 1;
    int row = gate * 256 + v * 32 + jf * 16 + l16;
    int col = kf * 32 + g * 8 + eh * 4;
    const float* W = dd ? Whh_b : Whh_f;
    float4 f = *(const float4*)(W + (size_t)row * 256 + col);
    unsigned int r01 = __builtin_amdgcn_cvt_pk_fp8_f32(f.x, f.y, 0u, false) & 0xffffu;
    unsigned int r23 = __builtin_amdgcn_cvt_pk_fp8_f32(f.z, f.w, 0u, false) & 0xffffu;
    WhhF8[q] = r01 | (r23 << 16);
  }
}

// ---------------- gather + pack A: [32768][448] bf16 ----------------
__global__ __launch_bounds__(256) void pack_A(const int* __restrict__ data,
    const int* __restrict__ onerad, const float* __restrict__ embed,
    const float* __restrict__ rad, u16* __restrict__ A) {
  int idx = blockIdx.x * 256 + threadIdx.x;
  int m = idx / 112;
  int c = idx - m * 112;
  int k0 = c * 4;
  float4 vv;
  if (k0 < 128)      vv = *(const float4*)(embed + (size_t)data[m] * 128 + k0);
  else if (k0 < 228) vv = *(const float4*)(rad + (size_t)onerad[m] * 100 + (k0 - 128));
  else if (k0 < 328) vv = *(const float4*)(rad + (size_t)onerad[32768 + m] * 100 + (k0 - 228));
  else if (k0 < 428) vv = *(const float4*)(rad + (size_t)onerad[65536 + m] * 100 + (k0 - 328));
  else               vv = make_float4(0.f, 0.f, 0.f, 0.f);
  u16x4 o4 = { f2b(vv.x), f2b(vv.y), f2b(vv.z), f2b(vv.w) };
  *(u16x4*)(A + (size_t)m * 448 + k0) = o4;
}

// ---------------- xg GEMM: X2 = gate-major(A @ Wih^T + bias) ----------------
// X2 u16 layout per d (33554432 u16): idx = R*1024 + v*128 + jf*64 + l16*4 + gate,
// R = m*256+t; col = d*1024 + gate*256 + v*32 + jf*16 + l16.
__global__ __launch_bounds__(256) void gemm_xg(const u16* __restrict__ A,
    const u16* __restrict__ Bw, const float* __restrict__ bias,
    u16* __restrict__ X2) {
  __shared__ u16 As[4096];
  __shared__ u16 Bs[4096];
  int bid = blockIdx.x;
  int mt = bid >> 4, nt = bid & 15;
  int m0 = mt * 128, n0 = nt * 128;
  int tid = threadIdx.x;
  int w = tid >> 6, lane = tid & 63, l16 = lane & 15, g = lane >> 4;
  int wr = w >> 1, wc = w & 1;
  int srow = tid >> 2, sch = tid & 3;
  f32x4 zero4 = {0.f, 0.f, 0.f, 0.f};
  f32x4 acc[4][4];
#pragma unroll
  for (int i = 0; i < 4; ++i)
#pragma unroll
    for (int j = 0; j < 4; ++j) acc[i][j] = zero4;
  for (int kk = 0; kk < 14; ++kk) {
    int kb = kk * 32;
    gload16(A + (size_t)(m0 + srow) * 448 + kb + sch * 8, (char*)As + tid * 16);
    gload16(A + (size_t)(m0 + srow + 64) * 448 + kb + sch * 8, (char*)As + 4096 + tid * 16);
    gload16(Bw + (size_t)(n0 + srow) * 448 + kb + sch * 8, (char*)Bs + tid * 16);
    gload16(Bw + (size_t)(n0 + srow + 64) * 448 + kb + sch * 8, (char*)Bs + 4096 + tid * 16);
    __syncthreads();
    bf16x8 af[4], bfr[4];
#pragma unroll
    for (int i = 0; i < 4; ++i) {
      af[i]  = *(const bf16x8*)((const char*)As + (wr * 64 + i * 16 + l16) * 64 + g * 16);
      bfr[i] = *(const bf16x8*)((const char*)Bs + (wc * 64 + i * 16 + l16) * 64 + g * 16);
    }
#pragma unroll
    for (int i = 0; i < 4; ++i)
#pragma unroll
      for (int j = 0; j < 4; ++j)
        acc[i][j] = MFMA(af[i], bfr[j], acc[i][j]);
    __syncthreads();
  }
  float bv[4];
#pragma unroll
  for (int j = 0; j < 4; ++j) bv[j] = bias[n0 + wc * 64 + j * 16 + l16];
#pragma unroll
  for (int i = 0; i < 4; ++i)
#pragma unroll
    for (int j = 0; j < 4; ++j) {
      int col = n0 + wc * 64 + j * 16 + l16;
      int dd = col >> 10, c = col & 1023;
      int gate = c >> 8, hid = c & 255;
      int vv = hid >> 5, jf2 = (hid >> 4) & 1, lc = hid & 15;
      size_t base = (size_t)dd * 33554432 + (size_t)vv * 128 + jf2 * 64 + lc * 4 + gate;
#pragma unroll
      for (int r = 0; r < 4; ++r) {
        int row = m0 + wr * 64 + i * 16 + g * 4 + r;
        X2[base + (size_t)row * 1024] = f2b(acc[i][j][r] + bv[j]);
      }
    }
}

// ---------------- LSTM recurrence: 32 blocks, one 8-row chunk each ----------------
// 32 blocks x 512 thr (2 dir x 16 chunks of 8 batch rows). Whh pinned
// (64 longs/lane). MFMA M=16 tile, rows 8-15 zero. Activations
// lane-redistributed: lower 32 lanes = jf0 cols, upper = jf1 via shfl_xor(32);
// each lane: 4 outputs (rows gl*4+r, col v*32+jfL*16+l16). h fp8 A-frags in
// LDS double-buffered; ONE fence/step.
#define PIN(n) long q##n; \
  asm volatile("global_load_dwordx2 %0, %1, off" : "=v"(q##n) : "v"(wbase + (n) * 512));
#define MMG(acc, gj, bn) \
  acc[gj] = __builtin_amdgcn_mfma_f32_16x16x32_fp8_fp8(a, bn, acc[gj], 0, 0, 0);
#define KSTEP(acc, fr, kf, B0, B1, B2, B3, B4, B5, B6, B7) { \
  long a = fr[(kf) * 64 + lane]; \
  MMG(acc, 0, B0) MMG(acc, 1, B1) MMG(acc, 2, B2) MMG(acc, 3, B3) \
  MMG(acc, 4, B4) MMG(acc, 5, B5) MMG(acc, 6, B6) MMG(acc, 7, B7) }
#define MFMA_PHASE(acc, hf) { \
  const long* fr = (const long*)(hf); \
  acc[0] = zero4; acc[1] = zero4; acc[2] = zero4; acc[3] = zero4; \
  acc[4] = zero4; acc[5] = zero4; acc[6] = zero4; acc[7] = zero4; \
  KSTEP(acc, fr, 0, q0, q8,  q16, q24, q32, q40, q48, q56) \
  KSTEP(acc, fr, 1, q1, q9,  q17, q25, q33, q41, q49, q57) \
  KSTEP(acc, fr, 2, q2, q10, q18, q26, q34, q42, q50, q58) \
  KSTEP(acc, fr, 3, q3, q11, q19, q27, q35, q43, q51, q59) \
  KSTEP(acc, fr, 4, q4, q12, q20, q28, q36, q44, q52, q60) \
  KSTEP(acc, fr, 5, q5, q13, q21, q29, q37, q45, q53, q61) \
  KSTEP(acc, fr, 6, q6, q14, q22, q30, q38, q46, q54, q62) \
  KSTEP(acc, fr, 7, q7, q15, q23, q31, q39, q47, q55, q63) }
#define TRANS(acc, cst, hf, sb, px) { \
  _Pragma("unroll") \
  for (int r = 0; r < 4; ++r) { \
    float o0 = __shfl_xor(acc[1][r], 32); \
    float o1 = __shfl_xor(acc[3][r], 32); \
    float o2 = __shfl_xor(acc[5][r], 32); \
    float o3 = __shfl_xor(acc[7][r], 32); \
    float iv = (lo32 ? acc[0][r] : o0) + b2lo(px[r].x); \
    float fv = (lo32 ? acc[2][r] : o1) + b2hi(px[r].x); \
    float gv = (lo32 ? acc[4][r] : o2) + b2lo(px[r].y); \
    float ov = (lo32 ? acc[6][r] : o3) + b2hi(px[r].y); \
    float cn = sigf(fv) * cst[r] + sigf(iv) * tanh_(gv); \
    cst[r] = cn; \
    float hv = sigf(ov) * tanh_(cn); \
    hf[fwoff + r * 8] = \
        (unsigned char)__builtin_amdgcn_cvt_pk_fp8_f32(hv, hv, 0u, false); \
    *(u16*)(sb[r] + voff_st) = f2b(hv); \
  } }
#define BUMP4(p, s) { p[0] += s; p[1] += s; p[2] += s; p[3] += s; }
#define LOADPX(px, pb) { \
  px[0] = *(const uint2*)(pb[0] + voff_px); \
  px[1] = *(const uint2*)(pb[1] + voff_px); \
  px[2] = *(const uint2*)(pb[2] + voff_px); \
  px[3] = *(const uint2*)(pb[3] + voff_px); }
#define FENCE { __builtin_amdgcn_sched_barrier(0); \
  asm volatile("s_waitcnt lgkmcnt(0)"); \
  __builtin_amdgcn_s_barrier(); \
  __builtin_amdgcn_sched_barrier(0); }

__global__ __launch_bounds__(512, 1) void lstm_recur(const u16* __restrict__ xg,
    const unsigned char* __restrict__ WhhF8, u16* __restrict__ outh) {
  __shared__ unsigned char hfA[2][4096];
  int blk = blockIdx.x;
  int d = blk >> 4, c8 = blk & 15;
  int rowA0 = c8 * 8;
  int tid = threadIdx.x;
  int v = tid >> 6, lane = tid & 63, l16 = lane & 15, g = lane >> 4;
  int jfL = g >> 1, gl = g & 1;
  bool lo32 = (lane < 32);

  const char* wbase = (const char*)WhhF8 + ((size_t)(d * 8 + v) * 4096 + lane) * 8;
  PIN(0)  PIN(1)  PIN(2)  PIN(3)  PIN(4)  PIN(5)  PIN(6)  PIN(7)
  PIN(8)  PIN(9)  PIN(10) PIN(11) PIN(12) PIN(13) PIN(14) PIN(15)
  PIN(16) PIN(17) PIN(18) PIN(19) PIN(20) PIN(21) PIN(22) PIN(23)
  PIN(24) PIN(25) PIN(26) PIN(27) PIN(28) PIN(29) PIN(30) PIN(31)
  PIN(32) PIN(33) PIN(34) PIN(35) PIN(36) PIN(37) PIN(38) PIN(39)
  PIN(40) PIN(41) PIN(42) PIN(43) PIN(44) PIN(45) PIN(46) PIN(47)
  PIN(48) PIN(49) PIN(50) PIN(51) PIN(52) PIN(53) PIN(54) PIN(55)
  PIN(56) PIN(57) PIN(58) PIN(59) PIN(60) PIN(61) PIN(62) PIN(63)

  for (int i = tid; i < 2048; i += 512) ((int*)hfA)[i] = 0;

  int t0 = d ? 255 : 0;
  int tpx = d ? -2048 : 2048;    // bytes per t-step in X2 (1024 u16/row-step)
  int tob = d ? -1024 : 1024;    // bytes per t-step in outh (512 u16)

  const char* X2b = (const char*)xg + (size_t)d * 67108864;
  char* outhb = (char*)outh;
  const char* pbA[4];
  char* sbA[4];
#pragma unroll
  for (int r = 0; r < 4; ++r) {
    pbA[r] = X2b + ((size_t)(rowA0 + r) * 256 + t0) * 2048;
    sbA[r] = outhb + (((size_t)(rowA0 + r) * 256 + t0) * 512 + d * 256) * 2;
  }
  // gl*4-row offsets baked into the lane offsets:
  int voff_px = gl * 2097152 + (v * 128 + jfL * 64 + l16 * 4) * 2;
  int voff_st = gl * 1048576 + (v * 32 + jfL * 16 + l16) * 2;
  int fwoff = (v * 64 + jfL * 32 + (l16 >> 3) * 16 + gl * 4) * 8 + (l16 & 7);

  uint2 pxA[4];
  LOADPX(pxA, pbA);

  asm volatile("s_waitcnt vmcnt(0)" ::: "memory");
  __builtin_amdgcn_sched_barrier(0);

  f32x4 zero4 = {0.f, 0.f, 0.f, 0.f};
  f32x4 cstA = zero4;
  f32x4 accA[8];
  __syncthreads();

#pragma unroll 1
  for (int tt = 0; tt < 256; ++tt) {
    int p = tt & 1;
    MFMA_PHASE(accA, &hfA[p][0]);
    {
      unsigned char* hf = &hfA[p ^ 1][0];
      TRANS(accA, cstA, hf, sbA, pxA);
    }
    BUMP4(sbA, tob); BUMP4(pbA, tpx);
    LOADPX(pxA, pbA);
    FENCE;
  }
}

// ---------------- emission: [32768][33] f32 = outh @ Wcls^T + bcls ----------------
__global__ __launch_bounds__(256) void emis_k(const u16* __restrict__ outh,
    const u16* __restrict__ WclsP, const float* __restrict__ bcls,
    float* __restrict__ emiB) {
  int tid = threadIdx.x;
  int w = tid >> 6, lane = tid & 63, l16 = lane & 15, g = lane >> 4;
  int mrow = blockIdx.x * 64 + w * 16;
  f32x4 zero4 = {0.f, 0.f, 0.f, 0.f};
  f32x4 acc[3] = {zero4, zero4, zero4};
#pragma unroll
  for (int kf = 0; kf < 16; ++kf) {
    bf16x8 a = *(const bf16x8*)(outh + (size_t)(mrow + l16) * 512 + kf * 32 + g * 8);
#pragma unroll
    for (int nf = 0; nf < 3; ++nf) {
      bf16x8 bb = *(const bf16x8*)(WclsP + (size_t)(nf * 16 + l16) * 512 + kf * 32 + g * 8);
      acc[nf] = MFMA(a, bb, acc[nf]);
    }
  }
#pragma unroll
  for (int nf = 0; nf < 3; ++nf) {
    int c = nf * 16 + l16;
    if (c < 33) {
      float bc = bcls[c];
#pragma unroll
      for (int r = 0; r < 4; ++r)
        emiB[(size_t)(mrow + g * 4 + r) * 33 + c] = acc[nf][r] + bc;
    }
  }
}

// ---------------- golden path score per batch row ----------------
__global__ __launch_bounds__(256) void golden_k(const int* __restrict__ tag,
    const float* __restrict__ emiB, const float* __restrict__ T,
    float* __restrict__ gpart) {
  int b = blockIdx.x, l = threadIdx.x;
  int tg = tag[b * 256 + l];
  float val = 0.f;
  if (tg != 0) {
    int prev = (l == 0) ? 31 : tag[b * 256 + l - 1];
    val = emiB[(size_t)(b * 256 + l) * 33 + tg] + T[prev * 33 + tg];
  }
#pragma unroll
  for (int o = 32; o > 0; o >>= 1) val += __shfl_down(val, o);
  __shared__ float red[4];
  if ((threadIdx.x & 63) == 0) red[threadIdx.x >> 6] = val;
  __syncthreads();
  if (threadIdx.x == 0) gpart[b] = red[0] + red[1] + red[2] + red[3];
}

// ---------------- CRF forward (logsumexp scan), 1 wave per batch row ----------------
__global__ __launch_bounds__(64) void crf_k(const int* __restrict__ tag,
    const float* __restrict__ emiB, const float* __restrict__ T,
    float* __restrict__ endsc) {
  int b = blockIdx.x;
  int lane = threadIdx.x;
  __shared__ float Ts[1089];
  __shared__ float sc[33];
  for (int i = lane; i < 1089; i += 64) Ts[i] = T[i];
  int cnt = 0;
  for (int i = lane; i < 256; i += 64) cnt += (tag[b * 256 + i] != 0) ? 1 : 0;
#pragma unroll
  for (int o = 1; o < 64; o <<= 1) cnt += __shfl_xor(cnt, o);
  int len = cnt;
  __syncthreads();
  int c = lane;
  float tcol[33];
  if (c < 33) {
#pragma unroll
    for (int p = 0; p < 33; ++p) tcol[p] = Ts[p * 33 + c];
    sc[c] = emiB[(size_t)(b * 256) * 33 + c] + tcol[31];   // START=31
  }
  __syncthreads();
#pragma unroll 1
  for (int t = 1; t < 256; ++t) {
    if (t >= len) break;
    float nv = 0.f;
    if (c < 33) {
      float ec = emiB[(size_t)(b * 256 + t) * 33 + c];
      float vb[33];
      float mx = -3.0e38f;
#pragma unroll
      for (int p = 0; p < 33; ++p) { vb[p] = sc[p] + tcol[p]; mx = fmaxf(mx, vb[p]); }
      float s = 0.f;
#pragma unroll
      for (int p = 0; p < 33; ++p) s += __expf(vb[p] - mx);
      nv = ec + mx + __logf(s);
    }
    __syncthreads();
    if (c < 33) sc[c] = nv;
    __syncthreads();
  }
  if (lane == 0) endsc[b] = sc[32];   // END=32
}

// ---------------- finalize ----------------
__global__ __launch_bounds__(64) void fin_k(const float* __restrict__ gpart,
    const float* __restrict__ endsc, float* __restrict__ out) {
  int l = threadIdx.x;
  float v = (endsc[l] - gpart[l]) + (endsc[l + 64] - gpart[l + 64]);
#pragma unroll
  for (int o = 32; o > 0; o >>= 1) v += __shfl_down(v, o);
  if (l == 0) out[0] = v / 128.f;
}

extern "C" void kernel_launch(void* const* d_in, const int* in_sizes, int n_in,
                              void* d_out, int out_size, void* d_ws, size_t ws_size,
                              hipStream_t stream) {
  const int*   batch_data   = (const int*)d_in[0];
  const int*   batch_onerad = (const int*)d_in[1];
  const int*   batch_tag    = (const int*)d_in[2];
  const float* embed        = (const float*)d_in[3];
  const float* rad_embed    = (const float*)d_in[4];
  const float* Wih_f = (const float*)d_in[5];
  const float* Whh_f = (const float*)d_in[6];
  const float* bih_f = (const float*)d_in[7];
  const float* bhh_f = (const float*)d_in[8];
  const float* Wih_b = (const float*)d_in[9];
  const float* Whh_b = (const float*)d_in[10];
  const float* bih_b = (const float*)d_in[11];
  const float* bhh_b = (const float*)d_in[12];
  const float* Wcls  = (const float*)d_in[13];
  const float* bcls  = (const float*)d_in[14];
  const float* trans = (const float*)d_in[15];

  // workspace layout (~203.9 MB)
  char* ws = (char*)d_ws;
  u16*   Apack = (u16*)  (ws + 0);            // 29360128
  u16*   X2    = (u16*)  (ws + 29360128);     // 134217728 (gate-major xg)
  u16*   WihP  = (u16*)  (ws + 163577856);    // 1835008
  unsigned int* WhhF8 = (unsigned int*)(ws + 165412864); // 524288
  float* biasP = (float*)(ws + 165937152);    // 8192
  u16*   WclsP = (u16*)  (ws + 165945344);    // 49152
  u16*   outh  = (u16*)  (ws + 165994496);    // 33554432
  float* emiB  = (float*)(ws + 199548928);    // 4325376
  float* gpart = (float*)(ws + 203874304);    // 512
  float* endsc = (float*)(ws + 203874816);    // 512

  pack_weights<<<4200, 256, 0, stream>>>(Wih_f, Wih_b, Whh_f, Whh_b, bih_f, bhh_f,
                                         bih_b, bhh_b, Wcls, WihP, WhhF8, biasP, WclsP);
  pack_A<<<14336, 256, 0, stream>>>(batch_data, batch_onerad, embed, rad_embed, Apack);
  gemm_xg<<<4096, 256, 0, stream>>>(Apack, WihP, biasP, X2);
  lstm_recur<<<32, 512, 0, stream>>>(X2, (const unsigned char*)WhhF8, outh);
  emis_k<<<512, 256, 0, stream>>>(outh, WclsP, bcls, emiB);
  golden_k<<<128, 256, 0, stream>>>(batch_tag, emiB, trans, gpart);
  crf_k<<<128, 64, 0, stream>>>(batch_tag, emiB, trans, endsc);
  fin_k<<<1, 64, 0, stream>>>(gpart, endsc, (float*)d_out);
}